// Round 3
// baseline (2087.702 us; speedup 1.0000x reference)
//
// MultiFactorAttention MI355X pipeline — Round 3 (dtype-adaptive + small ws)
//
// Kills both remaining failure hypotheses:
//  - runtime dtype detection (bf16 vs fp32 input buffers), uniform flag in ws,
//    dual-path loads everywhere; output written in the detected dtype.
//  - workspace cut to 49.4 MB (<64 MiB) via 4 passes of 16 batches for K/V.
//
//  k_detect   : flag = is_bf16(y_hat bits); biases -> float ws arrays
//  k_wtrans   : WqT/WsT/WkT/WvT (bf16, transposed for B-operand)
//  per pass p (16 batches): k_kvgemm (K[s][d], VT[d][s]) ; k_fused
//  k_softmax_final ; k_output

#include <hip/hip_runtime.h>
#include <hip/hip_bf16.h>

typedef __bf16 bf16_t;
typedef bf16_t bf16x8 __attribute__((ext_vector_type(8)));
typedef bf16_t bf16x4 __attribute__((ext_vector_type(4)));
typedef float  floatx4 __attribute__((ext_vector_type(4)));

#define MFMA16(a,b,c) __builtin_amdgcn_mfma_f32_16x16x32_bf16((a),(b),(c),0,0,0)

constexpr int T_ = 1024, TF_ = 512, S_ = 1536, F_ = 32;
constexpr int BPP = 16;                       // batches per pass
constexpr float INV_SCALE = 0.04419417382415922f;  // 1/sqrt(512)

// ---- dual-path load helpers (isbf is wave-uniform) ----
__device__ __forceinline__ bf16x8 load8(const void* p, size_t idx, int isbf) {
    if (isbf) return *(const bf16x8*)((const bf16_t*)p + idx);
    const floatx4* f = (const floatx4*)((const float*)p + idx);
    floatx4 a = f[0], b = f[1];
    bf16x8 r;
    r[0]=(bf16_t)a[0]; r[1]=(bf16_t)a[1]; r[2]=(bf16_t)a[2]; r[3]=(bf16_t)a[3];
    r[4]=(bf16_t)b[0]; r[5]=(bf16_t)b[1]; r[6]=(bf16_t)b[2]; r[7]=(bf16_t)b[3];
    return r;
}
__device__ __forceinline__ float loadf(const void* p, size_t idx, int isbf) {
    return isbf ? (float)((const bf16_t*)p)[idx] : ((const float*)p)[idx];
}

// ---------------- dtype detect + bias normalize ----------------
__global__ __launch_bounds__(256) void k_detect(
    const void* __restrict__ y, int* __restrict__ flag,
    const void* __restrict__ bq, const void* __restrict__ bk,
    const void* __restrict__ bv, const void* __restrict__ bs,
    float* __restrict__ bqf, float* __restrict__ bkf,
    float* __restrict__ bvf, float* __restrict__ bsf)
{
    __shared__ int cnt[4];
    const unsigned* w = (const unsigned*)y;
    unsigned x = w[threadIdx.x];
    unsigned e = (x >> 7) & 0xFFu;            // bf16-exponent field of LOW half
    bool hit = (e >= 100u && e <= 141u);      // plausible N(0,1) bf16 exponent
    unsigned long long m = __ballot(hit);
    if ((threadIdx.x & 63) == 0) cnt[threadIdx.x >> 6] = __popcll(m);
    __syncthreads();
    int isbf = (cnt[0] + cnt[1] + cnt[2] + cnt[3]) >= 128;
    if (threadIdx.x == 0) *flag = isbf;
    for (int i = threadIdx.x; i < 512; i += 256) {
        bqf[i] = loadf(bq, i, isbf);
        bkf[i] = loadf(bk, i, isbf);
        bvf[i] = loadf(bv, i, isbf);
        bsf[i] = loadf(bs, i, isbf);
    }
}

// ---------------- weight transposes (output always bf16) ----------------
__global__ __launch_bounds__(256) void k_wtrans(
    const void* __restrict__ Wq, const void* __restrict__ Ws,
    const void* __restrict__ Wk, const void* __restrict__ Wv,
    bf16_t* __restrict__ WqT, bf16_t* __restrict__ WsT,
    bf16_t* __restrict__ WkT, bf16_t* __restrict__ WvT,
    const int* __restrict__ flag)
{
    int isbf = *flag;
    int idx = blockIdx.x * 256 + threadIdx.x;
    if (idx < 262144) {                       // 512x512
        int k = idx >> 9, n = idx & 511;
        WqT[n * 512 + k] = (bf16_t)loadf(Wq, idx, isbf);
        WsT[n * 512 + k] = (bf16_t)loadf(Ws, idx, isbf);
    }
    if (idx < 16384) {                        // 32x512
        int f = idx >> 9, n = idx & 511;
        WkT[n * 32 + f] = (bf16_t)loadf(Wk, idx, isbf);
        WvT[n * 32 + f] = (bf16_t)loadf(Wv, idx, isbf);
    }
}

// ---------------- K,V GEMMs for one 16-batch pass ----------------
__global__ __launch_bounds__(256) void k_kvgemm(
    const void* __restrict__ hist, const void* __restrict__ fore,
    const bf16_t* __restrict__ WkT, const bf16_t* __restrict__ WvT,
    const float* __restrict__ bkf, const float* __restrict__ bvf,
    bf16_t* __restrict__ K, bf16_t* __restrict__ VT,
    const int* __restrict__ flag, int b0)
{
    int isbf = *flag;
    int wave = threadIdx.x >> 6, lane = threadIdx.x & 63;
    int l15 = lane & 15, quad = lane >> 4;
    int row0 = blockIdx.x * 16;               // local row in [0, BPP*S)
    int lb = row0 / S_;
    int s0 = row0 - lb * S_;
    int bg = b0 + lb;
    int n0 = wave * 128;
    int s = s0 + l15;
    const void* src; size_t eidx;
    if (s < T_) { src = hist; eidx = ((size_t)bg * T_ + s) * F_ + quad * 8; }
    else        { src = fore; eidx = ((size_t)bg * TF_ + (s - T_)) * F_ + quad * 8; }
    bf16x8 a = load8(src, eidx, isbf);
    floatx4 ak[8] = {}, av[8] = {};
#pragma unroll
    for (int nt = 0; nt < 8; ++nt) {
        bf16x8 bk_ = *(const bf16x8*)(WkT + (size_t)(n0 + nt * 16 + l15) * 32 + quad * 8);
        bf16x8 bv_ = *(const bf16x8*)(WvT + (size_t)(n0 + nt * 16 + l15) * 32 + quad * 8);
        ak[nt] = MFMA16(a, bk_, ak[nt]);
        av[nt] = MFMA16(a, bv_, av[nt]);
    }
#pragma unroll
    for (int nt = 0; nt < 8; ++nt) {
        int col = n0 + nt * 16 + l15;
        float bkv = bkf[col], bvv = bvf[col];
        bf16x4 vpack;
#pragma unroll
        for (int reg = 0; reg < 4; ++reg) {
            int row = row0 + quad * 4 + reg;
            K[(size_t)row * 512 + col] = (bf16_t)(ak[nt][reg] + bkv);
            vpack[reg] = (bf16_t)(av[nt][reg] + bvv);
        }
        int sl = s0 + quad * 4;
        *(bf16x4*)(VT + ((size_t)lb * 512 + col) * S_ + sl) = vpack;
    }
}

// ---------------- fused Q-GEMM + flash + epilogue GEMM/logits ----------------
__global__ __launch_bounds__(256) void k_fused(
    const void* __restrict__ Y, const bf16_t* __restrict__ WqT,
    const float* __restrict__ bqf, const bf16_t* __restrict__ Kg,
    const bf16_t* __restrict__ VT, const bf16_t* __restrict__ WsT,
    const float* __restrict__ bsf, float* __restrict__ logits,
    const int* __restrict__ flag, int b0)
{
    __shared__ union {
        float sc[4][32][68];        // 34816 B, flash score staging
        bf16_t tile[32][520];       // 33280 B, Q/corr tile staging (C->A layout)
    } u;
    __shared__ float l_lds[32];
    __shared__ float part[4][32];

    const int isbf = *flag;
    const int wave = threadIdx.x >> 6, lane = threadIdx.x & 63;
    const int l15 = lane & 15, quad = lane >> 4;
    const int lb = blockIdx.x >> 5;
    const int bg = b0 + lb;
    const int t0 = (blockIdx.x & 31) * 32;
    const int n0 = wave * 128;                 // this wave's 128-col (d) slice

    if (threadIdx.x < 32) l_lds[threadIdx.x] = 0.f;

    // ---- Phase A: Q tile = Y[t0..t0+32) @ Wq + bq ----
    {
        floatx4 acc[2][8] = {};
        const size_t abase0 = ((size_t)bg * T_ + t0 + l15) * 512 + quad * 8;
        const size_t abase1 = abase0 + 16 * 512;
        const bf16_t* bbase = WqT + (size_t)(n0 + l15) * 512 + quad * 8;
        for (int ks = 0; ks < 16; ++ks) {
            bf16x8 a0 = load8(Y, abase0 + ks * 32, isbf);
            bf16x8 a1 = load8(Y, abase1 + ks * 32, isbf);
#pragma unroll
            for (int nt = 0; nt < 8; ++nt) {
                bf16x8 bb = *(const bf16x8*)(bbase + (size_t)nt * 16 * 512 + ks * 32);
                acc[0][nt] = MFMA16(a0, bb, acc[0][nt]);
                acc[1][nt] = MFMA16(a1, bb, acc[1][nt]);
            }
        }
#pragma unroll
        for (int nt = 0; nt < 8; ++nt) {
            int col = n0 + nt * 16 + l15;
            float bqv = bqf[col];
#pragma unroll
            for (int mt = 0; mt < 2; ++mt)
#pragma unroll
                for (int reg = 0; reg < 4; ++reg)
                    u.tile[mt * 16 + quad * 4 + reg][col] = (bf16_t)(acc[mt][nt][reg] + bqv);
        }
    }
    __syncthreads();
    bf16x8 qf[2][4];                            // A-frags, this wave's d-slice
#pragma unroll
    for (int mt = 0; mt < 2; ++mt)
#pragma unroll
        for (int ks = 0; ks < 4; ++ks)
            qf[mt][ks] = *(const bf16x8*)&u.tile[mt * 16 + l15][n0 + ks * 32 + quad * 8];
    __syncthreads();                            // tile reads done; sc may overwrite

    // ---- Phase B: streaming attention, 24 chunks of 64 s ----
    floatx4 o[2][8] = {};
    const bf16_t* Kb = Kg + (size_t)lb * S_ * 512;
    const bf16_t* Vb = VT + (size_t)lb * 512 * S_;
    for (int c = 0; c < 24; ++c) {
        int sBase = c * 64;
        floatx4 scp[2][4] = {};                 // partial scores, this wave's d-slice
#pragma unroll
        for (int nt = 0; nt < 4; ++nt)
#pragma unroll
            for (int ks = 0; ks < 4; ++ks) {
                bf16x8 kf = *(const bf16x8*)(Kb + (size_t)(sBase + nt * 16 + l15) * 512
                                               + n0 + ks * 32 + quad * 8);
                scp[0][nt] = MFMA16(qf[0][ks], kf, scp[0][nt]);
                scp[1][nt] = MFMA16(qf[1][ks], kf, scp[1][nt]);
            }
        __syncthreads();                        // prior chunk's sc consumers done
#pragma unroll
        for (int mt = 0; mt < 2; ++mt)
#pragma unroll
            for (int nt = 0; nt < 4; ++nt)
#pragma unroll
                for (int reg = 0; reg < 4; ++reg)
                    u.sc[wave][mt * 16 + quad * 4 + reg][nt * 16 + l15] = scp[mt][nt][reg];
        __syncthreads();
        // rebuild P in A-operand layout (all waves build identical frags)
        bf16x8 pf[2][2];
        float rs[2];
#pragma unroll
        for (int mt = 0; mt < 2; ++mt) {
            float rowsum = 0.f;
#pragma unroll
            for (int kk = 0; kk < 2; ++kk) {
                int row = mt * 16 + l15, colb = kk * 32 + quad * 8;
                float v[8];
#pragma unroll
                for (int j = 0; j < 8; ++j)
                    v[j] = u.sc[0][row][colb + j] + u.sc[1][row][colb + j]
                         + u.sc[2][row][colb + j] + u.sc[3][row][colb + j];
#pragma unroll
                for (int j = 0; j < 8; ++j) {
                    v[j] = __expf(v[j] * INV_SCALE);
                    rowsum += v[j];
                    pf[mt][kk][j] = (bf16_t)v[j];
                }
            }
            rs[mt] = rowsum;
        }
        if (wave == 0) {
#pragma unroll
            for (int mt = 0; mt < 2; ++mt) {
                float r = rs[mt];
                r += __shfl_xor(r, 16);
                r += __shfl_xor(r, 32);
                if (quad == 0) l_lds[mt * 16 + l15] += r;
            }
        }
#pragma unroll
        for (int nt = 0; nt < 8; ++nt)
#pragma unroll
            for (int kk = 0; kk < 2; ++kk) {
                bf16x8 vf = *(const bf16x8*)(Vb + (size_t)(n0 + nt * 16 + l15) * S_
                                               + sBase + kk * 32 + quad * 8);
                o[0][nt] = MFMA16(pf[0][kk], vf, o[0][nt]);
                o[1][nt] = MFMA16(pf[1][kk], vf, o[1][nt]);
            }
    }
    __syncthreads();                            // l_lds final; sc reads all done

    // ---- Phase C: corr tile -> LDS, corr@Ws + bs, dot y_hat -> logits ----
#pragma unroll
    for (int mt = 0; mt < 2; ++mt)
#pragma unroll
        for (int reg = 0; reg < 4; ++reg) {
            float li = 1.f / l_lds[mt * 16 + quad * 4 + reg];
#pragma unroll
            for (int nt = 0; nt < 8; ++nt)
                u.tile[mt * 16 + quad * 4 + reg][n0 + nt * 16 + l15] =
                    (bf16_t)(o[mt][nt][reg] * li);
        }
    __syncthreads();
    {
        floatx4 acc[2][8] = {};
        const bf16_t* bbase = WsT + (size_t)(n0 + l15) * 512 + quad * 8;
        for (int ks = 0; ks < 16; ++ks) {
            bf16x8 a0 = *(const bf16x8*)&u.tile[l15][ks * 32 + quad * 8];
            bf16x8 a1 = *(const bf16x8*)&u.tile[16 + l15][ks * 32 + quad * 8];
#pragma unroll
            for (int nt = 0; nt < 8; ++nt) {
                bf16x8 bb = *(const bf16x8*)(bbase + (size_t)nt * 16 * 512 + ks * 32);
                acc[0][nt] = MFMA16(a0, bb, acc[0][nt]);
                acc[1][nt] = MFMA16(a1, bb, acc[1][nt]);
            }
        }
        float rsum[2][4] = {};
#pragma unroll
        for (int nt = 0; nt < 8; ++nt) {
            int col = n0 + nt * 16 + l15;
            float bsv = bsf[col];
#pragma unroll
            for (int mt = 0; mt < 2; ++mt)
#pragma unroll
                for (int reg = 0; reg < 4; ++reg) {
                    int row = t0 + mt * 16 + quad * 4 + reg;
                    float cv = acc[mt][nt][reg] + bsv;
                    rsum[mt][reg] += cv * loadf(Y, ((size_t)bg * T_ + row) * 512 + col, isbf);
                }
        }
#pragma unroll
        for (int mt = 0; mt < 2; ++mt)
#pragma unroll
            for (int reg = 0; reg < 4; ++reg) {
                float r = rsum[mt][reg];
                r += __shfl_xor(r, 1);
                r += __shfl_xor(r, 2);
                r += __shfl_xor(r, 4);
                r += __shfl_xor(r, 8);
                if (l15 == 0) part[wave][mt * 16 + quad * 4 + reg] = r;
            }
    }
    __syncthreads();
    if (threadIdx.x < 32) {
        float v = part[0][threadIdx.x] + part[1][threadIdx.x]
                + part[2][threadIdx.x] + part[3][threadIdx.x];
        logits[bg * 1024 + t0 + threadIdx.x] = v * INV_SCALE;
    }
}

// ---------------- softmax over T + pooled final ----------------
__global__ __launch_bounds__(512) void k_softmax_final(
    const float* __restrict__ logits, const void* __restrict__ Y,
    float* __restrict__ fin, const int* __restrict__ flag)
{
    __shared__ float P[1024];
    __shared__ float red[8];
    __shared__ float sval;
    int isbf = *flag;
    int b = blockIdx.x, tid = threadIdx.x;
    float l0 = logits[b * 1024 + tid];
    float l1 = logits[b * 1024 + 512 + tid];
    float m = fmaxf(l0, l1);
#pragma unroll
    for (int off = 1; off < 64; off <<= 1) m = fmaxf(m, __shfl_xor(m, off));
    if ((tid & 63) == 0) red[tid >> 6] = m;
    __syncthreads();
    if (tid == 0) { float mm = red[0]; for (int i = 1; i < 8; ++i) mm = fmaxf(mm, red[i]); sval = mm; }
    __syncthreads();
    float mx = sval;
    float e0 = __expf(l0 - mx), e1 = __expf(l1 - mx);
    float sacc = e0 + e1;
#pragma unroll
    for (int off = 1; off < 64; off <<= 1) sacc += __shfl_xor(sacc, off);
    if ((tid & 63) == 0) red[tid >> 6] = sacc;
    __syncthreads();
    if (tid == 0) { float ss = 0; for (int i = 0; i < 8; ++i) ss += red[i]; sval = ss; }
    __syncthreads();
    float inv = 1.f / sval;
    P[tid] = e0 * inv;
    P[tid + 512] = e1 * inv;
    __syncthreads();
    float acc = 0.f;
    size_t ybase = (size_t)b * T_ * 512 + tid;
#pragma unroll 4
    for (int t = 0; t < 1024; ++t) acc += P[t] * loadf(Y, ybase + (size_t)t * 512, isbf);
    fin[b * 512 + tid] = acc;
}

// ---------------- out = y_hat + final (broadcast over T) ----------------
__global__ __launch_bounds__(256) void k_output(
    const void* __restrict__ Y, const float* __restrict__ fin,
    void* __restrict__ out, const int* __restrict__ flag)
{
    int isbf = *flag;
    size_t idx = ((size_t)blockIdx.x * 256 + threadIdx.x) * 8;
    int d = (int)(idx & 511);
    int b = (int)(idx >> 19);   // 1024*512 elements per batch
    const float* f = fin + b * 512 + d;
    if (isbf) {
        bf16x8 y = *(const bf16x8*)((const bf16_t*)Y + idx);
        bf16x8 o;
#pragma unroll
        for (int j = 0; j < 8; ++j) o[j] = (bf16_t)((float)y[j] + f[j]);
        *(bf16x8*)((bf16_t*)out + idx) = o;
    } else {
        const floatx4* yp = (const floatx4*)((const float*)Y + idx);
        floatx4 y0 = yp[0], y1 = yp[1], o0, o1;
#pragma unroll
        for (int j = 0; j < 4; ++j) { o0[j] = y0[j] + f[j]; o1[j] = y1[j] + f[j + 4]; }
        floatx4* op = (floatx4*)((float*)out + idx);
        op[0] = o0; op[1] = o1;
    }
}

extern "C" void kernel_launch(void* const* d_in, const int* in_sizes, int n_in,
                              void* d_out, int out_size, void* d_ws, size_t ws_size,
                              hipStream_t stream)
{
    const void* y_hat = d_in[0];
    const void* hist  = d_in[1];
    const void* fore  = d_in[2];
    const void* Wq    = d_in[3];
    const void* bq    = d_in[4];
    const void* Wk    = d_in[5];
    const void* bk    = d_in[6];
    const void* Wv    = d_in[7];
    const void* bv    = d_in[8];
    const void* Ws    = d_in[9];
    const void* bs    = d_in[10];

    // workspace layout — total 51,847,184 B (49.4 MiB), all offsets 16B-aligned
    char* ws = (char*)d_ws;
    int*    flag   = (int*)   (ws);               // 16 B reserved
    float*  bqf    = (float*) (ws + 16);          // 2048 B
    float*  bkf    = (float*) (ws + 2064);
    float*  bvf    = (float*) (ws + 4112);
    float*  bsf    = (float*) (ws + 6160);
    bf16_t* WqT    = (bf16_t*)(ws + 8208);        // 524,288 B
    bf16_t* WsT    = (bf16_t*)(ws + 532496);      // 524,288 B
    bf16_t* WkT    = (bf16_t*)(ws + 1056784);     //  32,768 B
    bf16_t* WvT    = (bf16_t*)(ws + 1089552);     //  32,768 B
    float*  logits = (float*) (ws + 1122320);     // 262,144 B
    float*  finalb = (float*) (ws + 1384464);     // 131,072 B
    bf16_t* Kbuf   = (bf16_t*)(ws + 1515536);     // 25,165,824 B (16 batches)
    bf16_t* VTbuf  = (bf16_t*)(ws + 26681360);    // 25,165,824 B

    k_detect<<<1, 256, 0, stream>>>(y_hat, flag, bq, bk, bv, bs, bqf, bkf, bvf, bsf);
    k_wtrans<<<1024, 256, 0, stream>>>(Wq, Ws, Wk, Wv, WqT, WsT, WkT, WvT, flag);
    for (int p = 0; p < 4; ++p) {
        int b0 = p * BPP;
        k_kvgemm<<<1536, 256, 0, stream>>>(hist, fore, WkT, WvT, bkf, bvf,
                                           Kbuf, VTbuf, flag, b0);
        k_fused<<<512, 256, 0, stream>>>(y_hat, WqT, bqf, Kbuf, VTbuf, WsT, bsf,
                                         logits, flag, b0);
    }
    k_softmax_final<<<64, 512, 0, stream>>>(logits, y_hat, finalb, flag);
    k_output<<<16384, 256, 0, stream>>>(y_hat, finalb, d_out, flag);
}